// Round 3
// baseline (884.212 us; speedup 1.0000x reference)
//
#include <hip/hip_runtime.h>

typedef unsigned short u16;
typedef short bf16x8 __attribute__((ext_vector_type(8)));
typedef short s16x4 __attribute__((ext_vector_type(4)));
typedef float f32x4 __attribute__((ext_vector_type(4)));

#define DEV __device__ __forceinline__

DEV float b2f(u16 u) { union { unsigned i; float f; } x; x.i = ((unsigned)u) << 16; return x.f; }
DEV u16 f2b(float f) {
  union { float f; unsigned i; } x; x.f = f;
  unsigned r = x.i + 0x7fffu + ((x.i >> 16) & 1u);
  return (u16)(r >> 16);
}

constexpr int V_ = 4, H_ = 16, P_ = 2048;
constexpr float SCALE = 0.11180339887498949f; // 80^-0.5

// ---------------- GEMM: C = A(MxK) @ B(KxN) + bias ----------------
// A: MODE 0 -> float32 (hidden), MODE 1 -> bf16 (attention out)
// B, bias: float32 always.
// MODE 0: scatter bf16 into Q[v][h][p][96], K[v][h][p][96], Vv[v][h][p][80] (N=3840)
// MODE 1: row-major FLOAT out (N=1280)  — d_out is f32 per reference dtype
template<int MODE>
__global__ __launch_bounds__(256) void gemm_k(const void* __restrict__ Av,
    const float* __restrict__ B, const float* __restrict__ bias,
    u16* __restrict__ O0, u16* __restrict__ O1, u16* __restrict__ O2,
    float* __restrict__ Of,
    int M, int N, int K)
{
  __shared__ u16 Asm[128 * 40];   // [row][k] stride 40
  __shared__ u16 Bsm[128 * 40];   // transposed: [n][k] stride 40
  const int tid = threadIdx.x;
  const int w = tid >> 6, lane = tid & 63, quad = lane >> 4, l16 = lane & 15;
  const int wm = w >> 1, wn = w & 1;
  const int m0 = blockIdx.y * 128, n0 = blockIdx.x * 128;

  const f32x4 zero4 = {0.f, 0.f, 0.f, 0.f};
  f32x4 acc[4][4];
#pragma unroll
  for (int i = 0; i < 4; ++i)
#pragma unroll
    for (int j = 0; j < 4; ++j) acc[i][j] = zero4;

  for (int k0 = 0; k0 < K; k0 += 32) {
    __syncthreads();
    if (MODE == 0) {
      // A is f32: 128x32 tile = 1024 float4 chunks, 4/thread
      const float* A = (const float*)Av;
#pragma unroll
      for (int t = 0; t < 4; ++t) {
        int c = t * 256 + tid;
        int row = c >> 3, kc = (c & 7) << 2;
        f32x4 vv = *(const f32x4*)(A + (size_t)(m0 + row) * K + k0 + kc);
        s16x4 sv;
#pragma unroll
        for (int j = 0; j < 4; ++j) sv[j] = (short)f2b(vv[j]);
        *(s16x4*)(Asm + row * 40 + kc) = sv;
      }
    } else {
      // A is bf16: 128x32 tile = 512 bf16x8 chunks, 2/thread
      const u16* A = (const u16*)Av;
#pragma unroll
      for (int t = 0; t < 2; ++t) {
        int c = t * 256 + tid;
        int row = c >> 2, kc = (c & 3) << 3;
        bf16x8 vv = *(const bf16x8*)(A + (size_t)(m0 + row) * K + k0 + kc);
        *(bf16x8*)(Asm + row * 40 + kc) = vv;
      }
    }
    // B tile 32x128 (f32) transposed into Bsm: 1024 float4 chunks, 4/thread
#pragma unroll
    for (int t = 0; t < 4; ++t) {
      int c = t * 256 + tid;
      int kr = c >> 5, nc = (c & 31) << 2;
      f32x4 vv = *(const f32x4*)(B + (size_t)(k0 + kr) * N + n0 + nc);
#pragma unroll
      for (int j = 0; j < 4; ++j) Bsm[(nc + j) * 40 + kr] = f2b(vv[j]);
    }
    __syncthreads();
    bf16x8 af[4], bfr[4];
#pragma unroll
    for (int mi = 0; mi < 4; ++mi)
      af[mi] = *(const bf16x8*)(Asm + (wm * 64 + mi * 16 + l16) * 40 + quad * 8);
#pragma unroll
    for (int ni = 0; ni < 4; ++ni)
      bfr[ni] = *(const bf16x8*)(Bsm + (wn * 64 + ni * 16 + l16) * 40 + quad * 8);
#pragma unroll
    for (int mi = 0; mi < 4; ++mi)
#pragma unroll
      for (int ni = 0; ni < 4; ++ni)
        acc[mi][ni] = __builtin_amdgcn_mfma_f32_16x16x32_bf16(af[mi], bfr[ni], acc[mi][ni], 0, 0, 0);
  }

  // epilogue: C/D layout col=lane&15, row=quad*4+reg (m89/m91 verified)
#pragma unroll
  for (int mi = 0; mi < 4; ++mi) {
#pragma unroll
    for (int ni = 0; ni < 4; ++ni) {
      int n = n0 + wn * 64 + ni * 16 + l16;
      float bb = bias[n];
#pragma unroll
      for (int r = 0; r < 4; ++r) {
        int m = m0 + wm * 64 + mi * 16 + quad * 4 + r;
        float val = acc[mi][ni][r] + bb;
        if (MODE == 0) {
          int t = n / 1280, rr = n - t * 1280;
          int hh = rr / 80, dd = rr - hh * 80;
          int vv = m >> 11, p = m & 2047;
          int base = (vv * 16 + hh) * 2048 + p;
          if (t == 0)      O0[base * 96 + dd] = f2b(val);
          else if (t == 1) O1[base * 96 + dd] = f2b(val);
          else             O2[base * 80 + dd] = f2b(val);
        } else {
          Of[(size_t)m * N + n] = val;
        }
      }
    }
  }
}

// ---------------- RoPE (in place on Q,K; scale folded into Q) ----------------
__global__ __launch_bounds__(256) void rope_k(u16* __restrict__ Q, u16* __restrict__ K,
                                              const float* __restrict__ rope)
{
  constexpr int TOT = V_ * H_ * P_ * 40;  // 5,242,880 per tensor
  int idx = blockIdx.x * 256 + threadIdx.x;
  int which = idx >= TOT ? 1 : 0;
  int r = which ? idx - TOT : idx;
  int d = r % 40;
  int t1 = r / 40;           // = (v*16+h)*2048 + p
  int p = t1 & 2047;
  int t2 = t1 >> 11;
  int hh = t2 & 15;
  int vv = t2 >> 4;
  u16* buf = which ? K : Q;
  int base = ((vv * 16 + hh) * 2048 + p) * 96;
  int rc = (vv * 2048 + p) * 160;
  float x0 = b2f(buf[base + d]), x1 = b2f(buf[base + d + 40]);
  float c0 = rope[rc + d], c1 = rope[rc + d + 40];
  float s0 = rope[rc + 80 + d], s1 = rope[rc + 80 + d + 40];
  float y0 = x0 * c0 - x1 * s0;   // rot[d<40] = -x[d+40]
  float y1 = x1 * c1 + x0 * s1;   // rot[d>=40] = x[d-40]
  if (!which) { y0 *= SCALE; y1 *= SCALE; }
  buf[base + d] = f2b(y0);
  buf[base + d + 40] = f2b(y1);
}

// ---------------- Flash attention ----------------
// grid (P/64, H, V); block 256 = 4 waves x 16 q-rows. K-dim padded to 96.
__global__ __launch_bounds__(256) void attn_k(const u16* __restrict__ Q,
    const u16* __restrict__ K, const u16* __restrict__ V,
    const int* __restrict__ lens, u16* __restrict__ O)
{
  __shared__ u16 Ksm[64 * 104];   // [key][d] stride 104
  __shared__ u16 Vt[80 * 72];     // [d][key] stride 72
  __shared__ u16 Psm[4][16 * 72]; // per-wave P: [qrow][key] stride 72
  const int v = blockIdx.z, h = blockIdx.y, q0 = blockIdx.x * 64;
  const int tid = threadIdx.x, w = tid >> 6, lane = tid & 63;
  const int quad = lane >> 4, l16 = lane & 15;
  int len = lens[v]; if (len < 1) len = 1;
  const int vh = v * 16 + h;

  bf16x8 qf[3];
  {
    const u16* qp = Q + (size_t)(vh * 2048 + q0 + w * 16 + l16) * 96 + quad * 8;
#pragma unroll
    for (int kf = 0; kf < 3; ++kf) qf[kf] = *(const bf16x8*)(qp + kf * 32);
  }
  const f32x4 zero4 = {0.f, 0.f, 0.f, 0.f};
  f32x4 o[5];
#pragma unroll
  for (int i = 0; i < 5; ++i) o[i] = zero4;
  float m_run[4] = {-3e38f, -3e38f, -3e38f, -3e38f};
  float l_run[4] = {0.f, 0.f, 0.f, 0.f};

  for (int key0 = 0; key0 < len; key0 += 64) {
    __syncthreads();
    // stage K tile 64x96: 768 chunks, 3/thread
#pragma unroll
    for (int t = 0; t < 3; ++t) {
      int c = t * 256 + tid;
      int kr = c / 12, dc = c - kr * 12;
      bf16x8 vv = *(const bf16x8*)(K + (size_t)(vh * 2048 + key0 + kr) * 96 + dc * 8);
      *(bf16x8*)(Ksm + kr * 104 + dc * 8) = vv;
    }
    // stage V tile 64x80 transposed: 640 chunks
#pragma unroll
    for (int t = 0; t < 3; ++t) {
      int c = t * 256 + tid;
      if (c < 640) {
        int kr = c / 10, dc = c - kr * 10;
        bf16x8 vv = *(const bf16x8*)(V + (size_t)(vh * 2048 + key0 + kr) * 80 + dc * 8);
#pragma unroll
        for (int j = 0; j < 8; ++j) Vt[(dc * 8 + j) * 72 + kr] = (u16)vv[j];
      }
    }
    __syncthreads();

    // S = Q K^T (scale pre-folded into Q)
    f32x4 s[4];
#pragma unroll
    for (int i = 0; i < 4; ++i) s[i] = zero4;
#pragma unroll
    for (int ks = 0; ks < 3; ++ks)
#pragma unroll
      for (int ni = 0; ni < 4; ++ni) {
        bf16x8 kb = *(const bf16x8*)(Ksm + (ni * 16 + l16) * 104 + ks * 32 + quad * 8);
        s[ni] = __builtin_amdgcn_mfma_f32_16x16x32_bf16(qf[ks], kb, s[ni], 0, 0, 0);
      }
    // mask
#pragma unroll
    for (int ni = 0; ni < 4; ++ni) {
      int key = key0 + ni * 16 + l16;
      if (key >= len) {
#pragma unroll
        for (int r = 0; r < 4; ++r) s[ni][r] = -1e9f;
      }
    }
    // online softmax; row r of this lane's quad = q0 + w*16 + quad*4 + r
    float mx[4];
#pragma unroll
    for (int r = 0; r < 4; ++r) mx[r] = fmaxf(fmaxf(s[0][r], s[1][r]), fmaxf(s[2][r], s[3][r]));
#pragma unroll
    for (int off = 1; off < 16; off <<= 1)
#pragma unroll
      for (int r = 0; r < 4; ++r) mx[r] = fmaxf(mx[r], __shfl_xor(mx[r], off, 64));
    float alpha[4];
#pragma unroll
    for (int r = 0; r < 4; ++r) {
      float mn = fmaxf(m_run[r], mx[r]);
      alpha[r] = __expf(m_run[r] - mn);
      m_run[r] = mn;
    }
#pragma unroll
    for (int ni = 0; ni < 4; ++ni)
#pragma unroll
      for (int r = 0; r < 4; ++r) s[ni][r] = __expf(s[ni][r] - m_run[r]);
    float rs[4];
#pragma unroll
    for (int r = 0; r < 4; ++r) rs[r] = (s[0][r] + s[1][r]) + (s[2][r] + s[3][r]);
#pragma unroll
    for (int off = 1; off < 16; off <<= 1)
#pragma unroll
      for (int r = 0; r < 4; ++r) rs[r] += __shfl_xor(rs[r], off, 64);
#pragma unroll
    for (int r = 0; r < 4; ++r) l_run[r] = l_run[r] * alpha[r] + rs[r];
#pragma unroll
    for (int ni = 0; ni < 5; ++ni)
#pragma unroll
      for (int r = 0; r < 4; ++r) o[ni][r] *= alpha[r];
    // P: C-layout -> LDS -> A-layout (m120 pattern)
#pragma unroll
    for (int ni = 0; ni < 4; ++ni)
#pragma unroll
      for (int r = 0; r < 4; ++r)
        Psm[w][(quad * 4 + r) * 72 + ni * 16 + l16] = f2b(s[ni][r]);
    __syncthreads();
    // O += P V
#pragma unroll
    for (int ks = 0; ks < 2; ++ks) {
      bf16x8 pa = *(const bf16x8*)(&Psm[w][l16 * 72 + ks * 32 + quad * 8]);
#pragma unroll
      for (int ni = 0; ni < 5; ++ni) {
        bf16x8 vb = *(const bf16x8*)(Vt + (ni * 16 + l16) * 72 + ks * 32 + quad * 8);
        o[ni] = __builtin_amdgcn_mfma_f32_16x16x32_bf16(pa, vb, o[ni], 0, 0, 0);
      }
    }
  }
  float inv[4];
#pragma unroll
  for (int r = 0; r < 4; ++r) inv[r] = 1.0f / l_run[r];
#pragma unroll
  for (int ni = 0; ni < 5; ++ni)
#pragma unroll
    for (int r = 0; r < 4; ++r) {
      int qq = q0 + w * 16 + quad * 4 + r;
      O[((size_t)(v * 2048 + qq) * 16 + h) * 80 + ni * 16 + l16] = f2b(o[ni][r] * inv[r]);
    }
}

extern "C" void kernel_launch(void* const* d_in, const int* in_sizes, int n_in,
                              void* d_out, int out_size, void* d_ws, size_t ws_size,
                              hipStream_t stream) {
  const float* hidden = (const float*)d_in[0];
  const float* rope   = (const float*)d_in[1];
  const int*   lens   = (const int*)d_in[2];
  const float* w_qkv  = (const float*)d_in[3];
  const float* b_qkv  = (const float*)d_in[4];
  const float* w_proj = (const float*)d_in[5];
  const float* b_proj = (const float*)d_in[6];
  float* out = (float*)d_out;
  char* ws = (char*)d_ws;
  // Q: [4][16][2048][96] bf16 = 24 MB;  K: same;  V: [..][80] = 20 MB;  At: 20 MB
  u16* Qb = (u16*)(ws);
  u16* Kb = (u16*)(ws + 25165824);
  u16* Vb = (u16*)(ws + 50331648);
  u16* At = (u16*)(ws + 71303168);
  hipMemsetAsync(Qb, 0, 50331648, stream);  // zero Q,K incl. d=80..95 pad lanes
  gemm_k<0><<<dim3(30, 64), 256, 0, stream>>>(hidden, w_qkv, b_qkv, Qb, Kb, Vb, nullptr, 8192, 3840, 1280);
  rope_k<<<40960, 256, 0, stream>>>(Qb, Kb, rope);
  attn_k<<<dim3(32, 16, 4), 256, 0, stream>>>(Qb, Kb, Vb, lens, At);
  gemm_k<1><<<dim3(10, 64), 256, 0, stream>>>(At, w_proj, b_proj, nullptr, nullptr, nullptr, out, 8192, 1280, 1280);
}

// Round 4
// 517.667 us; speedup vs baseline: 1.7081x; 1.7081x over previous
//
#include <hip/hip_runtime.h>

typedef unsigned short u16;
typedef short bf16x8 __attribute__((ext_vector_type(8)));
typedef float f32x4 __attribute__((ext_vector_type(4)));

#define DEV __device__ __forceinline__

DEV float b2f(u16 u) { union { unsigned i; float f; } x; x.i = ((unsigned)u) << 16; return x.f; }
DEV u16 f2b(float f) {
  union { float f; unsigned i; } x; x.f = f;
  unsigned r = x.i + 0x7fffu + ((x.i >> 16) & 1u);
  return (u16)(r >> 16);
}

#define GLDS(gp, lp) __builtin_amdgcn_global_load_lds( \
    (const __attribute__((address_space(1))) void*)(gp), \
    (__attribute__((address_space(3))) void*)(lp), 16, 0, 0)

constexpr float SCALE = 0.11180339887498949f; // 80^-0.5

// ---------------- prep: f32 -> bf16 convert ----------------
__global__ __launch_bounds__(256) void cvt_k(const float* __restrict__ in,
                                             u16* __restrict__ out, int n) {
  int i = (blockIdx.x * 256 + threadIdx.x) * 8;
  if (i >= n) return;
  f32x4 a = *(const f32x4*)(in + i);
  f32x4 b = *(const f32x4*)(in + i + 4);
  bf16x8 o;
#pragma unroll
  for (int j = 0; j < 4; ++j) { o[j] = (short)f2b(a[j]); o[4 + j] = (short)f2b(b[j]); }
  *(bf16x8*)(out + i) = o;
}

// ---------------- prep: transpose f32[K][N] -> bf16[N][K] ----------------
__global__ __launch_bounds__(256) void transpose_k(const float* __restrict__ in,
                                                   u16* __restrict__ out, int K, int N) {
  __shared__ u16 tile[64 * 40];   // [n_local][k_local] stride 40
  const int tid = threadIdx.x;
  const int k0 = blockIdx.y * 32, n0 = blockIdx.x * 64;
#pragma unroll
  for (int t = 0; t < 2; ++t) {
    int c = t * 256 + tid;
    int k_l = c >> 4, n_l = (c & 15) << 2;
    f32x4 vv = *(const f32x4*)(in + (size_t)(k0 + k_l) * N + n0 + n_l);
#pragma unroll
    for (int j = 0; j < 4; ++j) tile[(n_l + j) * 40 + k_l] = f2b(vv[j]);
  }
  __syncthreads();
  int n_l = tid >> 2, kc = (tid & 3) << 3;
  bf16x8 vv = *(const bf16x8*)(tile + n_l * 40 + kc);
  *(bf16x8*)(out + (size_t)(n0 + n_l) * K + k0 + kc) = vv;
}

// ---------------- GEMM: C = A(MxK,bf16) @ Bt(NxK,bf16)^T + bias ----------------
// MODE 0: scatter bf16 Q[v][h][p][80], K[v][h][p][80], V^T[v][h][d][2048] (N=3840)
// MODE 1: row-major f32 out (N=1280)
// LDS: no padding (global_load_lds), XOR swizzle: 16B chunk q of row r stored at
// physical chunk q ^ ((r>>1)&3). Fragment ds_read_b128 is then <=2-way (free).
template<int MODE>
__global__ __launch_bounds__(256) void gemm_k(const u16* __restrict__ A,
    const u16* __restrict__ Bt, const float* __restrict__ bias,
    u16* __restrict__ Oq, u16* __restrict__ Ok, u16* __restrict__ Ov,
    float* __restrict__ Of, int M, int N, int K)
{
  __shared__ u16 Asm[128 * 32];
  __shared__ u16 Bsm[128 * 32];
  const int tid = threadIdx.x;
  const int w = tid >> 6, lane = tid & 63, quad = lane >> 4, l16 = lane & 15;
  const int wm = w >> 1, wn = w & 1;
  const int m0 = blockIdx.y * 128, n0 = blockIdx.x * 128;

  // per-lane staging constants: wave w covers rows [w*32, w*32+32), 2 loads of 16 rows
  const int srow0 = w * 32 + (lane >> 2);        // + t*16
  const int pchunk = lane & 3;

  const f32x4 zero4 = {0.f, 0.f, 0.f, 0.f};
  f32x4 acc[4][4];
#pragma unroll
  for (int i = 0; i < 4; ++i)
#pragma unroll
    for (int j = 0; j < 4; ++j) acc[i][j] = zero4;

  for (int k0 = 0; k0 < K; k0 += 32) {
    __syncthreads();
#pragma unroll
    for (int t = 0; t < 2; ++t) {
      int r = srow0 + t * 16;
      int q = pchunk ^ ((r >> 1) & 3);
      GLDS(A + (size_t)(m0 + r) * K + k0 + q * 8, Asm + r * 32 + pchunk * 8);
      GLDS(Bt + (size_t)(n0 + r) * K + k0 + q * 8, Bsm + r * 32 + pchunk * 8);
    }
    __syncthreads();
    bf16x8 af[4], bfr[4];
#pragma unroll
    for (int mi = 0; mi < 4; ++mi) {
      int lr = wm * 64 + mi * 16 + l16;
      af[mi] = *(const bf16x8*)(Asm + lr * 32 + ((quad ^ ((lr >> 1) & 3)) << 3));
    }
#pragma unroll
    for (int ni = 0; ni < 4; ++ni) {
      int nr = wn * 64 + ni * 16 + l16;
      bfr[ni] = *(const bf16x8*)(Bsm + nr * 32 + ((quad ^ ((nr >> 1) & 3)) << 3));
    }
#pragma unroll
    for (int mi = 0; mi < 4; ++mi)
#pragma unroll
      for (int ni = 0; ni < 4; ++ni)
        acc[mi][ni] = __builtin_amdgcn_mfma_f32_16x16x32_bf16(af[mi], bfr[ni], acc[mi][ni], 0, 0, 0);
  }

  // epilogue: C/D layout col=lane&15, row=quad*4+reg (m89/m91 verified)
#pragma unroll
  for (int mi = 0; mi < 4; ++mi) {
#pragma unroll
    for (int ni = 0; ni < 4; ++ni) {
      int n = n0 + wn * 64 + ni * 16 + l16;
      float bb = bias[n];
#pragma unroll
      for (int r = 0; r < 4; ++r) {
        int m = m0 + wm * 64 + mi * 16 + quad * 4 + r;
        float val = acc[mi][ni][r] + bb;
        if (MODE == 0) {
          int t = n / 1280, rr = n - t * 1280;
          int hh = rr / 80, dd = rr - hh * 80;
          int vv = m >> 11, p = m & 2047;
          int vh = vv * 16 + hh;
          if (t == 0)      Oq[(size_t)(vh * 2048 + p) * 80 + dd] = f2b(val);
          else if (t == 1) Ok[(size_t)(vh * 2048 + p) * 80 + dd] = f2b(val);
          else             Ov[((size_t)vh * 80 + dd) * 2048 + p] = f2b(val);
        } else {
          Of[(size_t)m * N + n] = val;
        }
      }
    }
  }
}

// ---------------- RoPE (in place on Q,K stride 80; scale folded into Q) -------
__global__ __launch_bounds__(256) void rope_k(u16* __restrict__ Q, u16* __restrict__ K,
                                              const float* __restrict__ rope)
{
  constexpr int TOT = 4 * 16 * 2048 * 40;  // 5,242,880 per tensor
  int idx = blockIdx.x * 256 + threadIdx.x;
  int which = idx >= TOT ? 1 : 0;
  int r = which ? idx - TOT : idx;
  int d = r % 40;
  int t1 = r / 40;           // = (v*16+h)*2048 + p
  int p = t1 & 2047;
  int vv = t1 >> 15;
  u16* buf = which ? K : Q;
  size_t base = (size_t)t1 * 80;
  int rc = (vv * 2048 + p) * 160;
  float x0 = b2f(buf[base + d]), x1 = b2f(buf[base + d + 40]);
  float c0 = rope[rc + d], c1 = rope[rc + d + 40];
  float s0 = rope[rc + 80 + d], s1 = rope[rc + 80 + d + 40];
  float y0 = x0 * c0 - x1 * s0;   // rot[d<40] = -x[d+40]
  float y1 = x1 * c1 + x0 * s1;   // rot[d>=40] = x[d-40]
  if (!which) { y0 *= SCALE; y1 *= SCALE; }
  buf[base + d] = f2b(y0);
  buf[base + d + 40] = f2b(y1);
}

// ---------------- Flash attention ----------------
// grid (P/64, H, V); block 256 = 4 waves x 16 q-rows. Q/K global stride 80,
// zero-padded to 96 in LDS/regs. V is pre-transposed [v][h][d][2048].
__global__ __launch_bounds__(256) void attn_k(const u16* __restrict__ Q,
    const u16* __restrict__ K, const u16* __restrict__ V,
    const int* __restrict__ lens, u16* __restrict__ O)
{
  __shared__ u16 Ksm[64 * 104];   // [key][d] stride 104, d 80..95 zeroed
  __shared__ u16 Vt[80 * 72];     // [d][key] stride 72
  __shared__ u16 Psm[4][16 * 72]; // per-wave P: [qrow][key] stride 72
  const int v = blockIdx.z, h = blockIdx.y, q0 = blockIdx.x * 64;
  const int tid = threadIdx.x, w = tid >> 6, lane = tid & 63;
  const int quad = lane >> 4, l16 = lane & 15;
  int len = lens[v]; if (len < 1) len = 1;
  const int vh = v * 16 + h;

  const bf16x8 zero8 = {0, 0, 0, 0, 0, 0, 0, 0};
  bf16x8 qf[3];
  {
    const u16* qp = Q + (size_t)(vh * 2048 + q0 + w * 16 + l16) * 80 + quad * 8;
    qf[0] = *(const bf16x8*)(qp);
    qf[1] = *(const bf16x8*)(qp + 32);
    qf[2] = (quad < 2) ? *(const bf16x8*)(qp + 64) : zero8;  // d=80..95 pad
  }
  const f32x4 zero4 = {0.f, 0.f, 0.f, 0.f};
  f32x4 o[5];
#pragma unroll
  for (int i = 0; i < 5; ++i) o[i] = zero4;
  float m_run[4] = {-3e38f, -3e38f, -3e38f, -3e38f};
  float l_run[4] = {0.f, 0.f, 0.f, 0.f};

  for (int key0 = 0; key0 < len; key0 += 64) {
    __syncthreads();
    // stage K tile 64x96 (d>=80 zero): 768 chunks, 3/thread
#pragma unroll
    for (int t = 0; t < 3; ++t) {
      int c = t * 256 + tid;
      int kr = c / 12, dc = c - kr * 12;
      bf16x8 vv = (dc < 10) ? *(const bf16x8*)(K + (size_t)(vh * 2048 + key0 + kr) * 80 + dc * 8)
                            : zero8;
      *(bf16x8*)(Ksm + kr * 104 + dc * 8) = vv;
    }
    // stage V^T tile 80(d) x 64(key): 640 chunks
#pragma unroll
    for (int t = 0; t < 3; ++t) {
      int c = t * 256 + tid;
      if (c < 640) {
        int d = c >> 3, kc = (c & 7) << 3;
        bf16x8 vv = *(const bf16x8*)(V + ((size_t)vh * 80 + d) * 2048 + key0 + kc);
        *(bf16x8*)(Vt + d * 72 + kc) = vv;
      }
    }
    __syncthreads();

    // S = Q K^T (scale pre-folded into Q)
    f32x4 s[4];
#pragma unroll
    for (int i = 0; i < 4; ++i) s[i] = zero4;
#pragma unroll
    for (int ks = 0; ks < 3; ++ks)
#pragma unroll
      for (int ni = 0; ni < 4; ++ni) {
        bf16x8 kb = *(const bf16x8*)(Ksm + (ni * 16 + l16) * 104 + ks * 32 + quad * 8);
        s[ni] = __builtin_amdgcn_mfma_f32_16x16x32_bf16(qf[ks], kb, s[ni], 0, 0, 0);
      }
    // mask
#pragma unroll
    for (int ni = 0; ni < 4; ++ni) {
      int key = key0 + ni * 16 + l16;
      if (key >= len) {
#pragma unroll
        for (int r = 0; r < 4; ++r) s[ni][r] = -1e9f;
      }
    }
    // online softmax; row r of this lane's quad = q0 + w*16 + quad*4 + r
    float mx[4];
#pragma unroll
    for (int r = 0; r < 4; ++r) mx[r] = fmaxf(fmaxf(s[0][r], s[1][r]), fmaxf(s[2][r], s[3][r]));
#pragma unroll
    for (int off = 1; off < 16; off <<= 1)
#pragma unroll
      for (int r = 0; r < 4; ++r) mx[r] = fmaxf(mx[r], __shfl_xor(mx[r], off, 64));
    float alpha[4];
#pragma unroll
    for (int r = 0; r < 4; ++r) {
      float mn = fmaxf(m_run[r], mx[r]);
      alpha[r] = __expf(m_run[r] - mn);
      m_run[r] = mn;
    }
#pragma unroll
    for (int ni = 0; ni < 4; ++ni)
#pragma unroll
      for (int r = 0; r < 4; ++r) s[ni][r] = __expf(s[ni][r] - m_run[r]);
    float rs[4];
#pragma unroll
    for (int r = 0; r < 4; ++r) rs[r] = (s[0][r] + s[1][r]) + (s[2][r] + s[3][r]);
#pragma unroll
    for (int off = 1; off < 16; off <<= 1)
#pragma unroll
      for (int r = 0; r < 4; ++r) rs[r] += __shfl_xor(rs[r], off, 64);
#pragma unroll
    for (int r = 0; r < 4; ++r) l_run[r] = l_run[r] * alpha[r] + rs[r];
#pragma unroll
    for (int ni = 0; ni < 5; ++ni)
#pragma unroll
      for (int r = 0; r < 4; ++r) o[ni][r] *= alpha[r];
    // P: C-layout -> LDS -> A-layout (m120 pattern)
#pragma unroll
    for (int ni = 0; ni < 4; ++ni)
#pragma unroll
      for (int r = 0; r < 4; ++r)
        Psm[w][(quad * 4 + r) * 72 + ni * 16 + l16] = f2b(s[ni][r]);
    __syncthreads();
    // O += P V
#pragma unroll
    for (int ks = 0; ks < 2; ++ks) {
      bf16x8 pa = *(const bf16x8*)(&Psm[w][l16 * 72 + ks * 32 + quad * 8]);
#pragma unroll
      for (int ni = 0; ni < 5; ++ni) {
        bf16x8 vb = *(const bf16x8*)(Vt + (ni * 16 + l16) * 72 + ks * 32 + quad * 8);
        o[ni] = __builtin_amdgcn_mfma_f32_16x16x32_bf16(pa, vb, o[ni], 0, 0, 0);
      }
    }
  }
  float inv[4];
#pragma unroll
  for (int r = 0; r < 4; ++r) inv[r] = 1.0f / l_run[r];
#pragma unroll
  for (int ni = 0; ni < 5; ++ni)
#pragma unroll
    for (int r = 0; r < 4; ++r) {
      int qq = q0 + w * 16 + quad * 4 + r;
      O[((size_t)(v * 2048 + qq) * 16 + h) * 80 + ni * 16 + l16] = f2b(o[ni][r] * inv[r]);
    }
}

extern "C" void kernel_launch(void* const* d_in, const int* in_sizes, int n_in,
                              void* d_out, int out_size, void* d_ws, size_t ws_size,
                              hipStream_t stream) {
  const float* hidden = (const float*)d_in[0];
  const float* rope   = (const float*)d_in[1];
  const int*   lens   = (const int*)d_in[2];
  const float* w_qkv  = (const float*)d_in[3];
  const float* b_qkv  = (const float*)d_in[4];
  const float* w_proj = (const float*)d_in[5];
  const float* b_proj = (const float*)d_in[6];
  float* out = (float*)d_out;
  char* ws = (char*)d_ws;
  // layout (bytes):
  //   [0,       21.0M) Ah (bf16 hidden) -> later reused as At (attn out)
  //   [21.0M,   30.8M) Bt_qkv (bf16 w_qkv^T) -> later reused as Bt_proj
  //   [30.8M,   51.8M) Q [v][h][p][80]
  //   [51.8M,   72.7M) K [v][h][p][80]
  //   [72.7M,   93.7M) V^T [v][h][d][2048]
  u16* Ah = (u16*)(ws);
  u16* Bt = (u16*)(ws + 20971520);
  u16* Qb = (u16*)(ws + 30801920);
  u16* Kb = (u16*)(ws + 51773440);
  u16* Vb = (u16*)(ws + 72744960);
  u16* At = Ah;
  u16* Bp = Bt;

  cvt_k<<<5120, 256, 0, stream>>>(hidden, Ah, 10485760);
  transpose_k<<<dim3(60, 40), 256, 0, stream>>>(w_qkv, Bt, 1280, 3840);
  gemm_k<0><<<dim3(30, 64), 256, 0, stream>>>(Ah, Bt, b_qkv, Qb, Kb, Vb, nullptr, 8192, 3840, 1280);
  rope_k<<<40960, 256, 0, stream>>>(Qb, Kb, rope);
  attn_k<<<dim3(32, 16, 4), 256, 0, stream>>>(Qb, Kb, Vb, lens, At);
  transpose_k<<<dim3(20, 40), 256, 0, stream>>>(w_proj, Bp, 1280, 1280);
  gemm_k<1><<<dim3(10, 64), 256, 0, stream>>>(At, Bp, b_proj, nullptr, nullptr, nullptr, out, 8192, 1280, 1280);
}

// Round 6
// 455.015 us; speedup vs baseline: 1.9433x; 1.1377x over previous
//
#include <hip/hip_runtime.h>

typedef unsigned short u16;
typedef short bf16x8 __attribute__((ext_vector_type(8)));
typedef short s16x4 __attribute__((ext_vector_type(4)));
typedef float f32x4 __attribute__((ext_vector_type(4)));

#define DEV __device__ __forceinline__

DEV float b2f(u16 u) { union { unsigned i; float f; } x; x.i = ((unsigned)u) << 16; return x.f; }
DEV u16 f2b(float f) {
  union { float f; unsigned i; } x; x.f = f;
  unsigned r = x.i + 0x7fffu + ((x.i >> 16) & 1u);
  return (u16)(r >> 16);
}

DEV float exp2g(float x) { return __builtin_amdgcn_exp2f(x); }

#define GLDS(gp, lp) __builtin_amdgcn_global_load_lds( \
    (const __attribute__((address_space(1))) void*)(gp), \
    (__attribute__((address_space(3))) void*)(lp), 16, 0, 0)

// Q pre-scale: 80^-0.5 * log2(e)  (softmax done in exp2 domain)
constexpr float QSCALE = 0.11180339887498949f * 1.4426950408889634f;

// ---------------- prep: cvt hidden -> bf16  +  transpose w_qkv ----------------
__global__ __launch_bounds__(256) void prep_k(const float* __restrict__ hidden,
    u16* __restrict__ Ah, const float* __restrict__ wq, u16* __restrict__ Btq)
{
  __shared__ u16 tile[64 * 40];
  int b = blockIdx.x, tid = threadIdx.x;
  if (b < 5120) {
    int i = (b * 256 + tid) * 8;
    f32x4 a = *(const f32x4*)(hidden + i);
    f32x4 c = *(const f32x4*)(hidden + i + 4);
    bf16x8 o;
#pragma unroll
    for (int j = 0; j < 4; ++j) { o[j] = (short)f2b(a[j]); o[4 + j] = (short)f2b(c[j]); }
    *(bf16x8*)(Ah + i) = o;
  } else {
    int tb = b - 5120;                 // 2400 blocks: 60 x 40
    int bx = tb % 60, by = tb / 60;
    const int Kd = 1280, Nd = 3840;
    int k0 = by * 32, n0 = bx * 64;
#pragma unroll
    for (int t = 0; t < 2; ++t) {
      int c = t * 256 + tid;
      int k_l = c >> 4, n_l = (c & 15) << 2;
      f32x4 vv = *(const f32x4*)(wq + (size_t)(k0 + k_l) * Nd + n0 + n_l);
#pragma unroll
      for (int j = 0; j < 4; ++j) tile[(n_l + j) * 40 + k_l] = f2b(vv[j]);
    }
    __syncthreads();
    int n_l = tid >> 2, kc = (tid & 3) << 3;
    bf16x8 vv = *(const bf16x8*)(tile + n_l * 40 + kc);
    *(bf16x8*)(Btq + (size_t)(n0 + n_l) * Kd + k0 + kc) = vv;
  }
}

// ---------------- GEMM: C = A(MxK,bf16) @ Bt(NxK,bf16)^T + bias ----------------
template<int MODE>
__global__ __launch_bounds__(256) void gemm_k(const u16* __restrict__ A,
    const u16* __restrict__ Bt, const float* __restrict__ bias,
    u16* __restrict__ Oq, u16* __restrict__ Ok, u16* __restrict__ Ov,
    float* __restrict__ Of, int M, int N, int K)
{
  __shared__ u16 Asm[128 * 32];
  __shared__ u16 Bsm[128 * 32];
  const int tid = threadIdx.x;
  const int w = tid >> 6, lane = tid & 63, quad = lane >> 4, l16 = lane & 15;
  const int wm = w >> 1, wn = w & 1;
  const int m0 = blockIdx.y * 128, n0 = blockIdx.x * 128;
  const int srow0 = w * 32 + (lane >> 2);
  const int pchunk = lane & 3;

  const f32x4 zero4 = {0.f, 0.f, 0.f, 0.f};
  f32x4 acc[4][4];
#pragma unroll
  for (int i = 0; i < 4; ++i)
#pragma unroll
    for (int j = 0; j < 4; ++j) acc[i][j] = zero4;

  for (int k0 = 0; k0 < K; k0 += 32) {
    __syncthreads();
#pragma unroll
    for (int t = 0; t < 2; ++t) {
      int r = srow0 + t * 16;
      int q = pchunk ^ ((r >> 1) & 3);
      GLDS(A + (size_t)(m0 + r) * K + k0 + q * 8, Asm + r * 32 + pchunk * 8);
      GLDS(Bt + (size_t)(n0 + r) * K + k0 + q * 8, Bsm + r * 32 + pchunk * 8);
    }
    __syncthreads();
    bf16x8 af[4], bfr[4];
#pragma unroll
    for (int mi = 0; mi < 4; ++mi) {
      int lr = wm * 64 + mi * 16 + l16;
      af[mi] = *(const bf16x8*)(Asm + lr * 32 + ((quad ^ ((lr >> 1) & 3)) << 3));
    }
#pragma unroll
    for (int ni = 0; ni < 4; ++ni) {
      int nr = wn * 64 + ni * 16 + l16;
      bfr[ni] = *(const bf16x8*)(Bsm + nr * 32 + ((quad ^ ((nr >> 1) & 3)) << 3));
    }
#pragma unroll
    for (int mi = 0; mi < 4; ++mi)
#pragma unroll
      for (int ni = 0; ni < 4; ++ni)
        acc[mi][ni] = __builtin_amdgcn_mfma_f32_16x16x32_bf16(af[mi], bfr[ni], acc[mi][ni], 0, 0, 0);
  }

#pragma unroll
  for (int mi = 0; mi < 4; ++mi) {
#pragma unroll
    for (int ni = 0; ni < 4; ++ni) {
      int n = n0 + wn * 64 + ni * 16 + l16;
      float bb = bias[n];
#pragma unroll
      for (int r = 0; r < 4; ++r) {
        int m = m0 + wm * 64 + mi * 16 + quad * 4 + r;
        float val = acc[mi][ni][r] + bb;
        if (MODE == 0) {
          int t = n / 1280, rr = n - t * 1280;
          int hh = rr / 80, dd = rr - hh * 80;
          int vv = m >> 11, p = m & 2047;
          int vh = vv * 16 + hh;
          if (t == 0)      Oq[(size_t)(vh * 2048 + p) * 80 + dd] = f2b(val);
          else if (t == 1) Ok[(size_t)(vh * 2048 + p) * 80 + dd] = f2b(val);
          else             Ov[((size_t)vh * 80 + dd) * 2048 + p] = f2b(val);
        } else {
          Of[(size_t)m * N + n] = val;
        }
      }
    }
  }
}

// -------- RoPE (in place on Q,K stride 80; QSCALE into Q)  +  w_proj transpose ----
__global__ __launch_bounds__(256) void rope_proj_k(u16* __restrict__ Q, u16* __restrict__ K,
    const float* __restrict__ rope, const float* __restrict__ wp, u16* __restrict__ Btp)
{
  __shared__ u16 tile[64 * 40];
  int b = blockIdx.x, tid = threadIdx.x;
  if (b < 40960) {
    constexpr int TOT = 4 * 16 * 2048 * 40;
    int idx = b * 256 + tid;
    int which = idx >= TOT ? 1 : 0;
    int r = which ? idx - TOT : idx;
    int d = r % 40;
    int t1 = r / 40;
    int p = t1 & 2047;
    int vv = t1 >> 15;
    u16* buf = which ? K : Q;
    size_t base = (size_t)t1 * 80;
    int rc = (vv * 2048 + p) * 160;
    float x0 = b2f(buf[base + d]), x1 = b2f(buf[base + d + 40]);
    float c0 = rope[rc + d], c1 = rope[rc + d + 40];
    float s0 = rope[rc + 80 + d], s1 = rope[rc + 80 + d + 40];
    float y0 = x0 * c0 - x1 * s0;
    float y1 = x1 * c1 + x0 * s1;
    if (!which) { y0 *= QSCALE; y1 *= QSCALE; }
    buf[base + d] = f2b(y0);
    buf[base + d + 40] = f2b(y1);
  } else {
    int tb = b - 40960;                // 800 blocks: 20 x 40
    int bx = tb % 20, by = tb / 20;
    const int Kd = 1280, Nd = 1280;
    int k0 = by * 32, n0 = bx * 64;
#pragma unroll
    for (int t = 0; t < 2; ++t) {
      int c = t * 256 + tid;
      int k_l = c >> 4, n_l = (c & 15) << 2;
      f32x4 vv = *(const f32x4*)(wp + (size_t)(k0 + k_l) * Nd + n0 + n_l);
#pragma unroll
      for (int j = 0; j < 4; ++j) tile[(n_l + j) * 40 + k_l] = f2b(vv[j]);
    }
    __syncthreads();
    int n_l = tid >> 2, kc = (tid & 3) << 3;
    bf16x8 vv = *(const bf16x8*)(tile + n_l * 40 + kc);
    *(bf16x8*)(Btp + (size_t)(n0 + n_l) * Kd + k0 + kc) = vv;
  }
}

// ---------------- Flash attention ----------------
// grid (P/64, H, V); block 256 = 4 waves x 16 q-rows.
// Ksm[64][96] XOR-swizzled (GLDS-staged, pad chunks read from zero global buf);
// Vt[96][64] XOR-swizzled [d][key] (GLDS-staged), row 80 = ones (l accumulator),
// rows 81..95 = 0. Softmax in exp2 domain (log2e folded into Q). P truncated to
// bf16; l sums the same truncated P via the ones column -> consistent normalize.
__global__ __launch_bounds__(256) void attn_k(const u16* __restrict__ Q,
    const u16* __restrict__ K, const u16* __restrict__ V,
    const int* __restrict__ lens, u16* __restrict__ O, const u16* __restrict__ zbuf)
{
  __shared__ u16 Ksm[64 * 96];
  __shared__ u16 Vt[96 * 64];
  __shared__ u16 Psm[4][16 * 72];
  const int v = blockIdx.z, h = blockIdx.y, q0 = blockIdx.x * 64;
  const int tid = threadIdx.x, w = tid >> 6, lane = tid & 63;
  const int quad = lane >> 4, l16 = lane & 15;
  int len = lens[v]; if (len < 1) len = 1;
  const int vh = v * 16 + h;

  // init Vt rows 80..95 once: d=80 -> 1.0, d=81..95 -> 0 (swizzle-invariant)
  if (tid < 128) {
    int row = 80 + (tid >> 3), pc = tid & 7;
    short val = (row == 80) ? (short)0x3F80 : (short)0;
    bf16x8 v8 = {val, val, val, val, val, val, val, val};
    *(bf16x8*)(Vt + row * 64 + pc * 8) = v8;
  }

  const bf16x8 zero8 = {0, 0, 0, 0, 0, 0, 0, 0};
  bf16x8 qf[3];
  {
    const u16* qp = Q + (size_t)(vh * 2048 + q0 + w * 16 + l16) * 80 + quad * 8;
    qf[0] = *(const bf16x8*)(qp);
    qf[1] = *(const bf16x8*)(qp + 32);
    qf[2] = (quad < 2) ? *(const bf16x8*)(qp + 64) : zero8;
  }

  // staging pointer precompute (static per lane; advance per iter)
  const u16* kp[3]; int kstr[3];
#pragma unroll
  for (int t = 0; t < 3; ++t) {
    int L = w * 192 + t * 64 + lane;
    int key = L / 12, pc = L - key * 12;
    int q = (pc < 8) ? (pc ^ (key & 7)) : (8 + ((pc - 8) ^ (key & 3)));
    bool valid = q < 10;
    kp[t] = valid ? (K + (size_t)(vh * 2048 + key) * 80 + q * 8) : zbuf;
    kstr[t] = valid ? 5120 : 0;
  }
  const u16* vp[3];
#pragma unroll
  for (int t = 0; t < 3; ++t) {
    int seg = w + t * 4;
    int d = seg * 8 + (lane >> 3), pc = lane & 7;
    int q = pc ^ (d & 7);
    vp[t] = V + ((size_t)vh * 80 + d) * 2048 + q * 8;   // used only if seg<10
  }

  const f32x4 zero4 = {0.f, 0.f, 0.f, 0.f};
  f32x4 o[6];
#pragma unroll
  for (int i = 0; i < 6; ++i) o[i] = zero4;
  float m_run[4] = {-3e38f, -3e38f, -3e38f, -3e38f};

  for (int key0 = 0; key0 < len; key0 += 64) {
    __syncthreads();
#pragma unroll
    for (int t = 0; t < 3; ++t) {
      GLDS(kp[t], Ksm + (w * 192 + t * 64) * 8);
      kp[t] += kstr[t];
    }
#pragma unroll
    for (int t = 0; t < 3; ++t) {
      int seg = w + t * 4;
      if (seg < 10) { GLDS(vp[t], Vt + seg * 512); vp[t] += 64; }
    }
    __syncthreads();

    // S = Q K^T (QSCALE pre-folded into Q; exp2 domain)
    f32x4 s[4];
#pragma unroll
    for (int i = 0; i < 4; ++i) s[i] = zero4;
#pragma unroll
    for (int ks = 0; ks < 3; ++ks) {
      int ph = (ks < 2) ? ((ks * 4 + quad) ^ (l16 & 7)) : (8 + (quad ^ (l16 & 3)));
#pragma unroll
      for (int ni = 0; ni < 4; ++ni) {
        bf16x8 kb = *(const bf16x8*)(Ksm + (ni * 16 + l16) * 96 + ph * 8);
        s[ni] = __builtin_amdgcn_mfma_f32_16x16x32_bf16(qf[ks], kb, s[ni], 0, 0, 0);
      }
    }
    // mask
#pragma unroll
    for (int ni = 0; ni < 4; ++ni) {
      int key = key0 + ni * 16 + l16;
      if (key >= len) {
#pragma unroll
        for (int r = 0; r < 4; ++r) s[ni][r] = -1e9f;
      }
    }
    // online softmax (rows = quad*4+r)
    float mx[4];
#pragma unroll
    for (int r = 0; r < 4; ++r) mx[r] = fmaxf(fmaxf(s[0][r], s[1][r]), fmaxf(s[2][r], s[3][r]));
#pragma unroll
    for (int off = 1; off < 16; off <<= 1)
#pragma unroll
      for (int r = 0; r < 4; ++r) mx[r] = fmaxf(mx[r], __shfl_xor(mx[r], off, 64));
    float alpha[4];
#pragma unroll
    for (int r = 0; r < 4; ++r) {
      float mn = fmaxf(m_run[r], mx[r]);
      alpha[r] = exp2g(m_run[r] - mn);
      m_run[r] = mn;
    }
#pragma unroll
    for (int ni = 0; ni < 4; ++ni)
#pragma unroll
      for (int r = 0; r < 4; ++r) s[ni][r] = exp2g(s[ni][r] - m_run[r]);
    // P -> per-wave LDS (truncate to bf16; no barrier needed, same wave)
#pragma unroll
    for (int ni = 0; ni < 4; ++ni)
#pragma unroll
      for (int r = 0; r < 4; ++r) {
        union { float f; unsigned u; } x; x.f = s[ni][r];
        Psm[w][(quad * 4 + r) * 72 + ni * 16 + l16] = (u16)(x.u >> 16);
      }
    // rescale accumulators (incl. l column)
#pragma unroll
    for (int ni = 0; ni < 6; ++ni)
#pragma unroll
      for (int r = 0; r < 4; ++r) o[ni][r] *= alpha[r];
    // O += P V   (ni=5 accumulates row-sum l via ones column)
#pragma unroll
    for (int ks = 0; ks < 2; ++ks) {
      bf16x8 pa = *(const bf16x8*)(&Psm[w][l16 * 72 + ks * 32 + quad * 8]);
      int ph = (ks * 4 + quad) ^ (l16 & 7);
#pragma unroll
      for (int ni = 0; ni < 6; ++ni) {
        bf16x8 vb = *(const bf16x8*)(Vt + (ni * 16 + l16) * 64 + ph * 8);
        o[ni] = __builtin_amdgcn_mfma_f32_16x16x32_bf16(pa, vb, o[ni], 0, 0, 0);
      }
    }
  }
  float inv[4];
#pragma unroll
  for (int r = 0; r < 4; ++r) {
    float l = __shfl(o[5][r], (lane & 48), 64);   // l lives at l16==0 of each quad
    inv[r] = 1.0f / l;
  }
#pragma unroll
  for (int ni = 0; ni < 5; ++ni)
#pragma unroll
    for (int r = 0; r < 4; ++r) {
      int qq = q0 + w * 16 + quad * 4 + r;
      O[((size_t)(v * 2048 + qq) * 16 + h) * 80 + ni * 16 + l16] = f2b(o[ni][r] * inv[r]);
    }
}

extern "C" void kernel_launch(void* const* d_in, const int* in_sizes, int n_in,
                              void* d_out, int out_size, void* d_ws, size_t ws_size,
                              hipStream_t stream) {
  const float* hidden = (const float*)d_in[0];
  const float* rope   = (const float*)d_in[1];
  const int*   lens   = (const int*)d_in[2];
  const float* w_qkv  = (const float*)d_in[3];
  const float* b_qkv  = (const float*)d_in[4];
  const float* w_proj = (const float*)d_in[5];
  const float* b_proj = (const float*)d_in[6];
  float* out = (float*)d_out;
  char* ws = (char*)d_ws;
  // [0, 21.0M) Ah (bf16 hidden) -> reused as At; [21.0M, 30.8M) Bt (qkv^T, later proj^T)
  // [30.8M, 51.8M) Q; [51.8M, 72.7M) K; [72.7M, 93.7M) V^T
  u16* Ah = (u16*)(ws);
  u16* Bt = (u16*)(ws + 20971520);
  u16* Qb = (u16*)(ws + 30801920);
  u16* Kb = (u16*)(ws + 51773440);
  u16* Vb = (u16*)(ws + 72744960);
  u16* At = Ah;
  u16* Bp = Bt;

  prep_k<<<7520, 256, 0, stream>>>(hidden, Ah, w_qkv, Bt);
  gemm_k<0><<<dim3(30, 64), 256, 0, stream>>>(Ah, Bt, b_qkv, Qb, Kb, Vb, nullptr, 8192, 3840, 1280);
  rope_proj_k<<<41760, 256, 0, stream>>>(Qb, Kb, rope, w_proj, Bp);
  attn_k<<<dim3(32, 16, 4), 256, 0, stream>>>(Qb, Kb, Vb, lens, At, (const u16*)b_qkv);
  gemm_k<1><<<dim3(10, 64), 256, 0, stream>>>(At, Bp, b_proj, nullptr, nullptr, nullptr, out, 8192, 1280, 1280);
}

// Round 7
// 402.748 us; speedup vs baseline: 2.1954x; 1.1298x over previous
//
#include <hip/hip_runtime.h>

typedef unsigned short u16;
typedef short bf16x8 __attribute__((ext_vector_type(8)));
typedef float f32x4 __attribute__((ext_vector_type(4)));

#define DEV __device__ __forceinline__

DEV float b2f(u16 u) { union { unsigned i; float f; } x; x.i = ((unsigned)u) << 16; return x.f; }
DEV u16 f2b(float f) {
  union { float f; unsigned i; } x; x.f = f;
  unsigned r = x.i + 0x7fffu + ((x.i >> 16) & 1u);
  return (u16)(r >> 16);
}

DEV float exp2g(float x) { return __builtin_amdgcn_exp2f(x); }

#define GLDS(gp, lp) __builtin_amdgcn_global_load_lds( \
    (const __attribute__((address_space(1))) void*)(gp), \
    (__attribute__((address_space(3))) void*)(lp), 16, 0, 0)

// Q pre-scale: 80^-0.5 * log2(e)  (softmax done in exp2 domain)
constexpr float QSCALE = 0.11180339887498949f * 1.4426950408889634f;

// ---------------- prep: cvt hidden -> bf16  +  transpose w_qkv ----------------
__global__ __launch_bounds__(256) void prep_k(const float* __restrict__ hidden,
    u16* __restrict__ Ah, const float* __restrict__ wq, u16* __restrict__ Btq)
{
  __shared__ u16 tile[64 * 40];
  int b = blockIdx.x, tid = threadIdx.x;
  if (b < 5120) {
    int i = (b * 256 + tid) * 8;
    f32x4 a = *(const f32x4*)(hidden + i);
    f32x4 c = *(const f32x4*)(hidden + i + 4);
    bf16x8 o;
#pragma unroll
    for (int j = 0; j < 4; ++j) { o[j] = (short)f2b(a[j]); o[4 + j] = (short)f2b(c[j]); }
    *(bf16x8*)(Ah + i) = o;
  } else {
    int tb = b - 5120;                 // 2400 blocks: 60 x 40
    int bx = tb % 60, by = tb / 60;
    const int Kd = 1280, Nd = 3840;
    int k0 = by * 32, n0 = bx * 64;
#pragma unroll
    for (int t = 0; t < 2; ++t) {
      int c = t * 256 + tid;
      int k_l = c >> 4, n_l = (c & 15) << 2;
      f32x4 vv = *(const f32x4*)(wq + (size_t)(k0 + k_l) * Nd + n0 + n_l);
#pragma unroll
      for (int j = 0; j < 4; ++j) tile[(n_l + j) * 40 + k_l] = f2b(vv[j]);
    }
    __syncthreads();
    int n_l = tid >> 2, kc = (tid & 3) << 3;
    bf16x8 vv = *(const bf16x8*)(tile + n_l * 40 + kc);
    *(bf16x8*)(Btq + (size_t)(n0 + n_l) * Kd + k0 + kc) = vv;
  }
}

// ---------------- GEMM: C = A(MxK,bf16) @ Bt(NxK,bf16)^T + bias ----------------
// BK=64. LDS unpadded, XOR-swizzled on the SOURCE address (GLDS dest must be
// lane-linear): chunk j of row r lives at physical chunk j ^ (r&7).
// MODE 0: scatter bf16 Q/K[v][h][p][80], V^T[v][h][d][2048]; skip K/V blocks
// fully beyond valid len (masked keys -> exp2(-1e9)=0; 0xAA poison is finite).
template<int MODE>
__global__ __launch_bounds__(256) void gemm_k(const u16* __restrict__ A,
    const u16* __restrict__ Bt, const float* __restrict__ bias,
    u16* __restrict__ Oq, u16* __restrict__ Ok, u16* __restrict__ Ov,
    float* __restrict__ Of, const int* __restrict__ lens, int M, int N, int K)
{
  __shared__ u16 Asm[128 * 64];
  __shared__ u16 Bsm[128 * 64];
  const int tid = threadIdx.x;
  const int w = tid >> 6, lane = tid & 63, quad = lane >> 4, l16 = lane & 15;
  const int wm = w >> 1, wn = w & 1;
  const int m0 = blockIdx.y * 128, n0 = blockIdx.x * 128;

  if (MODE == 0) {
    if (n0 >= 1280) {                 // K/V output region
      int vv = m0 >> 11, p0 = m0 & 2047;
      int len = lens[vv]; if (len < 1) len = 1;
      if (p0 >= len) return;          // uniform: whole tile past valid keys
    }
  }

  // staging: 4 GLDS per matrix; chunk c = g*256+tid -> row c>>3, pc c&7
  const int srow = tid >> 3, spc = tid & 7;

  const f32x4 zero4 = {0.f, 0.f, 0.f, 0.f};
  f32x4 acc[4][4];
#pragma unroll
  for (int i = 0; i < 4; ++i)
#pragma unroll
    for (int j = 0; j < 4; ++j) acc[i][j] = zero4;

  for (int k0 = 0; k0 < K; k0 += 64) {
    __syncthreads();
#pragma unroll
    for (int g = 0; g < 4; ++g) {
      int r = g * 32 + srow;
      int q = spc ^ (r & 7);
      GLDS(A + (size_t)(m0 + r) * K + k0 + q * 8, Asm + r * 64 + spc * 8);
      GLDS(Bt + (size_t)(n0 + r) * K + k0 + q * 8, Bsm + r * 64 + spc * 8);
    }
    __syncthreads();
#pragma unroll
    for (int ks = 0; ks < 2; ++ks) {
      bf16x8 af[4], bfr[4];
#pragma unroll
      for (int mi = 0; mi < 4; ++mi) {
        int lr = wm * 64 + mi * 16 + l16;
        int ph = (ks * 4 + quad) ^ (lr & 7);
        af[mi] = *(const bf16x8*)(Asm + lr * 64 + ph * 8);
      }
#pragma unroll
      for (int ni = 0; ni < 4; ++ni) {
        int nr = wn * 64 + ni * 16 + l16;
        int ph = (ks * 4 + quad) ^ (nr & 7);
        bfr[ni] = *(const bf16x8*)(Bsm + nr * 64 + ph * 8);
      }
#pragma unroll
      for (int mi = 0; mi < 4; ++mi)
#pragma unroll
        for (int ni = 0; ni < 4; ++ni)
          acc[mi][ni] = __builtin_amdgcn_mfma_f32_16x16x32_bf16(af[mi], bfr[ni], acc[mi][ni], 0, 0, 0);
    }
  }

#pragma unroll
  for (int mi = 0; mi < 4; ++mi) {
#pragma unroll
    for (int ni = 0; ni < 4; ++ni) {
      int n = n0 + wn * 64 + ni * 16 + l16;
      float bb = bias[n];
#pragma unroll
      for (int r = 0; r < 4; ++r) {
        int m = m0 + wm * 64 + mi * 16 + quad * 4 + r;
        float val = acc[mi][ni][r] + bb;
        if (MODE == 0) {
          int t = n / 1280, rr = n - t * 1280;
          int hh = rr / 80, dd = rr - hh * 80;
          int vv = m >> 11, p = m & 2047;
          int vh = vv * 16 + hh;
          if (t == 0)      Oq[(size_t)(vh * 2048 + p) * 80 + dd] = f2b(val);
          else if (t == 1) Ok[(size_t)(vh * 2048 + p) * 80 + dd] = f2b(val);
          else             Ov[((size_t)vh * 80 + dd) * 2048 + p] = f2b(val);
        } else {
          Of[(size_t)m * N + n] = val;
        }
      }
    }
  }
}

// -------- RoPE (in place on Q,K stride 80; QSCALE into Q)  +  w_proj transpose ----
__global__ __launch_bounds__(256) void rope_proj_k(u16* __restrict__ Q, u16* __restrict__ K,
    const float* __restrict__ rope, const float* __restrict__ wp, u16* __restrict__ Btp)
{
  __shared__ u16 tile[64 * 40];
  int b = blockIdx.x, tid = threadIdx.x;
  if (b < 40960) {
    constexpr int TOT = 4 * 16 * 2048 * 40;
    int idx = b * 256 + tid;
    int which = idx >= TOT ? 1 : 0;
    int r = which ? idx - TOT : idx;
    int d = r % 40;
    int t1 = r / 40;
    int p = t1 & 2047;
    int vv = t1 >> 15;
    u16* buf = which ? K : Q;
    size_t base = (size_t)t1 * 80;
    int rc = (vv * 2048 + p) * 160;
    float x0 = b2f(buf[base + d]), x1 = b2f(buf[base + d + 40]);
    float c0 = rope[rc + d], c1 = rope[rc + d + 40];
    float s0 = rope[rc + 80 + d], s1 = rope[rc + 80 + d + 40];
    float y0 = x0 * c0 - x1 * s0;
    float y1 = x1 * c1 + x0 * s1;
    if (!which) { y0 *= QSCALE; y1 *= QSCALE; }
    buf[base + d] = f2b(y0);
    buf[base + d + 40] = f2b(y1);
  } else {
    int tb = b - 40960;                // 800 blocks: 20 x 40
    int bx = tb % 20, by = tb / 20;
    const int Kd = 1280, Nd = 1280;
    int k0 = by * 32, n0 = bx * 64;
#pragma unroll
    for (int t = 0; t < 2; ++t) {
      int c = t * 256 + tid;
      int k_l = c >> 4, n_l = (c & 15) << 2;
      f32x4 vv = *(const f32x4*)(wp + (size_t)(k0 + k_l) * Nd + n0 + n_l);
#pragma unroll
      for (int j = 0; j < 4; ++j) tile[(n_l + j) * 40 + k_l] = f2b(vv[j]);
    }
    __syncthreads();
    int n_l = tid >> 2, kc = (tid & 3) << 3;
    bf16x8 vv = *(const bf16x8*)(tile + n_l * 40 + kc);
    *(bf16x8*)(Btp + (size_t)(n0 + n_l) * Kd + k0 + kc) = vv;
  }
}

// ---------------- Flash attention ----------------
__global__ __launch_bounds__(256) void attn_k(const u16* __restrict__ Q,
    const u16* __restrict__ K, const u16* __restrict__ V,
    const int* __restrict__ lens, u16* __restrict__ O, const u16* __restrict__ zbuf)
{
  __shared__ u16 Ksm[64 * 96];
  __shared__ u16 Vt[96 * 64];
  __shared__ u16 Psm[4][16 * 72];
  const int v = blockIdx.z, h = blockIdx.y, q0 = blockIdx.x * 64;
  const int tid = threadIdx.x, w = tid >> 6, lane = tid & 63;
  const int quad = lane >> 4, l16 = lane & 15;
  int len = lens[v]; if (len < 1) len = 1;
  const int vh = v * 16 + h;

  // init Vt rows 80..95 once: d=80 -> 1.0, d=81..95 -> 0 (swizzle-invariant)
  if (tid < 128) {
    int row = 80 + (tid >> 3), pc = tid & 7;
    short val = (row == 80) ? (short)0x3F80 : (short)0;
    bf16x8 v8 = {val, val, val, val, val, val, val, val};
    *(bf16x8*)(Vt + row * 64 + pc * 8) = v8;
  }

  const bf16x8 zero8 = {0, 0, 0, 0, 0, 0, 0, 0};
  bf16x8 qf[3];
  {
    const u16* qp = Q + (size_t)(vh * 2048 + q0 + w * 16 + l16) * 80 + quad * 8;
    qf[0] = *(const bf16x8*)(qp);
    qf[1] = *(const bf16x8*)(qp + 32);
    qf[2] = (quad < 2) ? *(const bf16x8*)(qp + 64) : zero8;
  }

  const u16* kp[3]; int kstr[3];
#pragma unroll
  for (int t = 0; t < 3; ++t) {
    int L = w * 192 + t * 64 + lane;
    int key = L / 12, pc = L - key * 12;
    int q = (pc < 8) ? (pc ^ (key & 7)) : (8 + ((pc - 8) ^ (key & 3)));
    bool valid = q < 10;
    kp[t] = valid ? (K + (size_t)(vh * 2048 + key) * 80 + q * 8) : zbuf;
    kstr[t] = valid ? 5120 : 0;
  }
  const u16* vp[3];
#pragma unroll
  for (int t = 0; t < 3; ++t) {
    int seg = w + t * 4;
    int d = seg * 8 + (lane >> 3), pc = lane & 7;
    int q = pc ^ (d & 7);
    vp[t] = V + ((size_t)vh * 80 + d) * 2048 + q * 8;
  }

  const f32x4 zero4 = {0.f, 0.f, 0.f, 0.f};
  f32x4 o[6];
#pragma unroll
  for (int i = 0; i < 6; ++i) o[i] = zero4;
  float m_run[4] = {-3e38f, -3e38f, -3e38f, -3e38f};

  for (int key0 = 0; key0 < len; key0 += 64) {
    __syncthreads();
#pragma unroll
    for (int t = 0; t < 3; ++t) {
      GLDS(kp[t], Ksm + (w * 192 + t * 64) * 8);
      kp[t] += kstr[t];
    }
#pragma unroll
    for (int t = 0; t < 3; ++t) {
      int seg = w + t * 4;
      if (seg < 10) { GLDS(vp[t], Vt + seg * 512); vp[t] += 64; }
    }
    __syncthreads();

    f32x4 s[4];
#pragma unroll
    for (int i = 0; i < 4; ++i) s[i] = zero4;
#pragma unroll
    for (int ks = 0; ks < 3; ++ks) {
      int ph = (ks < 2) ? ((ks * 4 + quad) ^ (l16 & 7)) : (8 + (quad ^ (l16 & 3)));
#pragma unroll
      for (int ni = 0; ni < 4; ++ni) {
        bf16x8 kb = *(const bf16x8*)(Ksm + (ni * 16 + l16) * 96 + ph * 8);
        s[ni] = __builtin_amdgcn_mfma_f32_16x16x32_bf16(qf[ks], kb, s[ni], 0, 0, 0);
      }
    }
#pragma unroll
    for (int ni = 0; ni < 4; ++ni) {
      int key = key0 + ni * 16 + l16;
      if (key >= len) {
#pragma unroll
        for (int r = 0; r < 4; ++r) s[ni][r] = -1e9f;
      }
    }
    float mx[4];
#pragma unroll
    for (int r = 0; r < 4; ++r) mx[r] = fmaxf(fmaxf(s[0][r], s[1][r]), fmaxf(s[2][r], s[3][r]));
#pragma unroll
    for (int off = 1; off < 16; off <<= 1)
#pragma unroll
      for (int r = 0; r < 4; ++r) mx[r] = fmaxf(mx[r], __shfl_xor(mx[r], off, 64));
    float alpha[4];
#pragma unroll
    for (int r = 0; r < 4; ++r) {
      float mn = fmaxf(m_run[r], mx[r]);
      alpha[r] = exp2g(m_run[r] - mn);
      m_run[r] = mn;
    }
#pragma unroll
    for (int ni = 0; ni < 4; ++ni)
#pragma unroll
      for (int r = 0; r < 4; ++r) s[ni][r] = exp2g(s[ni][r] - m_run[r]);
#pragma unroll
    for (int ni = 0; ni < 4; ++ni)
#pragma unroll
      for (int r = 0; r < 4; ++r) {
        union { float f; unsigned u; } x; x.f = s[ni][r];
        Psm[w][(quad * 4 + r) * 72 + ni * 16 + l16] = (u16)(x.u >> 16);
      }
#pragma unroll
    for (int ni = 0; ni < 6; ++ni)
#pragma unroll
      for (int r = 0; r < 4; ++r) o[ni][r] *= alpha[r];
#pragma unroll
    for (int ks = 0; ks < 2; ++ks) {
      bf16x8 pa = *(const bf16x8*)(&Psm[w][l16 * 72 + ks * 32 + quad * 8]);
      int ph = (ks * 4 + quad) ^ (l16 & 7);
#pragma unroll
      for (int ni = 0; ni < 6; ++ni) {
        bf16x8 vb = *(const bf16x8*)(Vt + (ni * 16 + l16) * 64 + ph * 8);
        o[ni] = __builtin_amdgcn_mfma_f32_16x16x32_bf16(pa, vb, o[ni], 0, 0, 0);
      }
    }
  }
  float inv[4];
#pragma unroll
  for (int r = 0; r < 4; ++r) {
    float l = __shfl(o[5][r], (lane & 48), 64);
    inv[r] = 1.0f / l;
  }
#pragma unroll
  for (int ni = 0; ni < 5; ++ni)
#pragma unroll
    for (int r = 0; r < 4; ++r) {
      int qq = q0 + w * 16 + quad * 4 + r;
      O[((size_t)(v * 2048 + qq) * 16 + h) * 80 + ni * 16 + l16] = f2b(o[ni][r] * inv[r]);
    }
}

extern "C" void kernel_launch(void* const* d_in, const int* in_sizes, int n_in,
                              void* d_out, int out_size, void* d_ws, size_t ws_size,
                              hipStream_t stream) {
  const float* hidden = (const float*)d_in[0];
  const float* rope   = (const float*)d_in[1];
  const int*   lens   = (const int*)d_in[2];
  const float* w_qkv  = (const float*)d_in[3];
  const float* b_qkv  = (const float*)d_in[4];
  const float* w_proj = (const float*)d_in[5];
  const float* b_proj = (const float*)d_in[6];
  float* out = (float*)d_out;
  char* ws = (char*)d_ws;
  u16* Ah = (u16*)(ws);
  u16* Bt = (u16*)(ws + 20971520);
  u16* Qb = (u16*)(ws + 30801920);
  u16* Kb = (u16*)(ws + 51773440);
  u16* Vb = (u16*)(ws + 72744960);
  u16* At = Ah;
  u16* Bp = Bt;

  prep_k<<<7520, 256, 0, stream>>>(hidden, Ah, w_qkv, Bt);
  gemm_k<0><<<dim3(30, 64), 256, 0, stream>>>(Ah, Bt, b_qkv, Qb, Kb, Vb, nullptr, lens, 8192, 3840, 1280);
  rope_proj_k<<<41760, 256, 0, stream>>>(Qb, Kb, rope, w_proj, Bp);
  attn_k<<<dim3(32, 16, 4), 256, 0, stream>>>(Qb, Kb, Vb, lens, At, (const u16*)b_qkv);
  gemm_k<1><<<dim3(10, 64), 256, 0, stream>>>(At, Bp, b_proj, nullptr, nullptr, nullptr, out, lens, 8192, 1280, 1280);
}